// Round 14
// baseline (627.605 us; speedup 1.0000x reference)
//
#include <hip/hip_runtime.h>
#include <stdint.h>

// ---------------------------------------------------------------------------
// BatchWhiten: out = x @ inv_sqrtm(max(0.1*running + 0.9*(x^T x)/N, 1e-5))
// x: [262144, 512] fp32, running: [512,512] fp32, out: [262144,512] fp32
// ---------------------------------------------------------------------------

#define N_ROWS 262144
#define D 512
#define NS_ITERS 3  // 1 simplified (Z0=I) + 1 full + 1 final Z-only (fused)
#define CK_CHUNKS 256
#define CK_ROWS (N_ROWS / CK_CHUNKS)  // 1024
#define BKC 32
#define CK_STEPS (CK_ROWS / BKC)      // 32

typedef float f32x4 __attribute__((ext_vector_type(4)));
typedef short s16x8 __attribute__((ext_vector_type(8)));
typedef short s16x4 __attribute__((ext_vector_type(4)));
typedef __bf16 bf16x8 __attribute__((ext_vector_type(8)));

static __device__ __forceinline__ unsigned short f2bf(float f) {
  unsigned u = __float_as_uint(f);
  u += 0x7FFFu + ((u >> 16) & 1u);  // RNE
  return (unsigned short)(u >> 16);
}

static __device__ __forceinline__ f32x4 mfma16(s16x8 a, s16x8 b, f32x4 c) {
  return __builtin_amdgcn_mfma_f32_16x16x32_bf16(
      __builtin_bit_cast(bf16x8, a), __builtin_bit_cast(bf16x8, b), c, 0, 0, 0);
}

// async global->LDS, 16B per lane; LDS dest = wave-uniform base + lane*16
static __device__ __forceinline__ void gld_lds16(const void* g, void* l) {
  __builtin_amdgcn_global_load_lds(
      (const __attribute__((address_space(1))) void*)g,
      (__attribute__((address_space(3))) void*)l, 16, 0, 0);
}

#define SWZ8(c) (((c) ^ ((c) >> 3)) & 7)

// Conflict-free covar LDS slot map (r11): 128-col subtile [128 c][32 k] bf16.
#define CVOFF(c, kc) \
  ((((c) >> 1) << 6) + ((((((kc) << 1) | ((c) & 1))) ^ SWZ8((c) >> 1)) << 3))
// 256-col tile = two 128-col subtiles. Subtile = 4096 SHORTS (r13 bug: used
// 8192 = the BYTE size, in a short* index space -> A subtile-1 overwrote B).
#define CVOFF256(c, kc) ((((c) >> 7) * 4096) + CVOFF((c) & 127, kc))

// BK=32 row swizzle for gemm tiles (rows = 32 shorts = 64B)
#define GSW(row, g) (((g) ^ (((row) >> 1) & 3)) << 3)

// raw barrier, LDS-writes published, NO vmcnt drain
static __device__ __forceinline__ void bar_lgkm() {
  asm volatile("s_waitcnt lgkmcnt(0)" ::: "memory");
  __builtin_amdgcn_s_barrier();
  __builtin_amdgcn_sched_barrier(0);
}

// ---------------------------------------------------------------------------
// Kernel 1: Cpart[xcd] += x^T x. 2x2 SUPER-TILES (256x256), 1024 thr/block,
// 16 waves of 64x64. 3 supers/chunk {(0,0),(0,1),(1,1)} vs 10 works ->
// staging amplification 4x -> 2x (halved f2bf VALU / loads / ds_writes).
// grid 768 = 3 supers x 256 chunks = 3 balanced rounds on 256 CUs; chunk
// fp32 slab = 2MB (XCD-L2 resident for the 3 hw-stride-8 co-sharers).
// Diag supers: waves 8-15 don't stage (B=A) and skip below-diagonal writes;
// their A-staging dumps xb16 (s0: cols 0-255, s2: 256-511 -> exact once).
// Reg-prefetch + LDS dbuf + lgkm-only barrier kept from r10/r11.
// ---------------------------------------------------------------------------
__global__ __launch_bounds__(1024) void covar_k(const float* __restrict__ x,
                                                float* __restrict__ Cpart,
                                                short* __restrict__ xb16) {
  __shared__ short ldsT[2][2][256 * 32];  // [dbuf][A,B][256x32 tile] = 64 KB

  // bijective XCD swizzle: 768 works = 8 XCDs x 96
  const int hw = blockIdx.x;
  const int work = (hw & 7) * 96 + (hw >> 3);
  const int s = work % 3;           // 0:(0,0) 1:(0,1) 2:(1,1)
  const int chunk = work / 3;
  const int mb2 = (s == 2) ? 1 : 0;
  const int nb2 = (s == 0) ? 0 : 1;
  const bool diag = (mb2 == nb2);
  float* C = Cpart + (size_t)(hw & 7) * (D * D);

  const int tid = threadIdx.x;
  const int lane = tid & 63;
  const int wave = tid >> 6;        // 0..15
  const int isB = wave >> 3;        // staging role: waves 0-7 A, 8-15 B
  const int st512 = tid & 511;      // index within staging half
  const int cp = st512 & 127;       // col-pair 0..127 -> cols 2cp,2cp+1
  const int kh = st512 >> 7;        // 0..3 -> k rows 8kh..8kh+7
  const int c2 = cp * 2;

  const int wr = wave >> 2, wc = wave & 3;  // 4x4 wave grid of 64x64 tiles
  const int l15 = lane & 15, g = lane >> 4;

  const bool doStage = (!isB) || (!diag);
  const int tileCol = (isB ? nb2 : mb2) * 256;

  const bool haveDump = (xb16 != nullptr);
  const bool dump = haveDump && diag && (!isB);  // diag A-stagers dump all
  uint32_t* xw = (uint32_t*)xb16;

  f32x4 acc[4][4];
#pragma unroll
  for (int i = 0; i < 4; ++i)
#pragma unroll
    for (int j = 0; j < 4; ++j) acc[i][j] = f32x4{0.f, 0.f, 0.f, 0.f};

  const size_t kbase0 = (size_t)chunk * CK_ROWS;
  const float* srcBase = x + (kbase0 + kh * 8) * D + tileCol + c2;

  // register prefetch (16 VGPR)
  float2 buf[8];
  if (doStage) {
#pragma unroll
    for (int q = 0; q < 8; ++q) buf[q] = *(const float2*)(srcBase + (size_t)q * D);
  }

  for (int st = 0; st < CK_STEPS; ++st) {
    if (doStage) {
      s16x8 p0, p1;
#pragma unroll
      for (int q = 0; q < 8; ++q) {
        p0[q] = (short)f2bf(buf[q].x);
        p1[q] = (short)f2bf(buf[q].y);
      }
      if (st + 1 < CK_STEPS) {
        const float* src = srcBase + (size_t)(st + 1) * BKC * D;
#pragma unroll
        for (int q = 0; q < 8; ++q) buf[q] = *(const float2*)(src + (size_t)q * D);
      }
      short* wp = ldsT[st & 1][isB];
      *(s16x8*)(wp + CVOFF256(c2, kh)) = p0;
      *(s16x8*)(wp + CVOFF256(c2 + 1, kh)) = p1;
      if (dump) {
        const size_t k0 = kbase0 + (size_t)st * BKC;
#pragma unroll
        for (int q = 0; q < 8; ++q) {
          const uint32_t u =
              (uint32_t)(uint16_t)p0[q] | ((uint32_t)(uint16_t)p1[q] << 16);
          __builtin_nontemporal_store(
              u, &xw[(k0 + kh * 8 + q) * 256 + (tileCol >> 1) + cp]);
        }
      }
    }

    bar_lgkm();  // publish ds_writes; NO vmcnt drain

    const short* rA = ldsT[st & 1][0];
    const short* rB = ldsT[st & 1][diag ? 0 : 1];
    s16x8 af[4], bfv[4];
#pragma unroll
    for (int mi = 0; mi < 4; ++mi) {
      const int m = 64 * wr + 16 * mi + l15;
      af[mi] = *(const s16x8*)(rA + CVOFF256(m, g));
    }
#pragma unroll
    for (int nj = 0; nj < 4; ++nj) {
      const int n = 64 * wc + 16 * nj + l15;
      bfv[nj] = *(const s16x8*)(rB + CVOFF256(n, g));
    }
#pragma unroll
    for (int mi = 0; mi < 4; ++mi)
#pragma unroll
      for (int nj = 0; nj < 4; ++nj)
        acc[mi][nj] = mfma16(af[mi], bfv[nj], acc[mi][nj]);
  }

  // epilogue: atomic accumulate (skip strictly-below-diagonal wave tiles)
  if (!(diag && wr > wc)) {
#pragma unroll
    for (int mi = 0; mi < 4; ++mi)
#pragma unroll
      for (int nj = 0; nj < 4; ++nj) {
        const int n = nb2 * 256 + 64 * wc + 16 * nj + l15;
#pragma unroll
        for (int r = 0; r < 4; ++r) {
          const int m = mb2 * 256 + 64 * wr + 16 * mi + 4 * g + r;
          atomicAdd(&C[(size_t)m * D + n], acc[mi][nj][r]);
        }
      }
  }
}

// ---------------------------------------------------------------------------
// Kernel 2: M = max(0.1*run + (0.9/N)*sum_p Cpart[p], 1e-5); sMax = max rowsum
// ---------------------------------------------------------------------------
__global__ __launch_bounds__(256) void prep_k(const float* __restrict__ Cpart,
                                              const float* __restrict__ run,
                                              float* __restrict__ M,
                                              unsigned* __restrict__ sMax) {
  const int r = blockIdx.x;
  const int t = threadIdx.x;
  const float cs = 0.9f / (float)N_ROWS;
  float sum = 0.f;
  for (int c = t; c < D; c += 256) {
    const int rr = r < c ? r : c;
    const int cc = r < c ? c : r;
    float cv = 0.f;
#pragma unroll
    for (int p = 0; p < 8; ++p)
      cv += Cpart[(size_t)p * D * D + (size_t)rr * D + cc];
    float v = 0.1f * run[(size_t)r * D + c] + cs * cv;
    v = fmaxf(v, 1e-5f);
    M[(size_t)r * D + c] = v;
    sum += v;
  }
  __shared__ float red[256];
  red[t] = sum;
  __syncthreads();
  for (int off = 128; off > 0; off >>= 1) {
    if (t < off) red[t] += red[t + off];
    __syncthreads();
  }
  if (t == 0) atomicMax(sMax, __float_as_uint(red[0]));
}

// ---------------------------------------------------------------------------
// Kernel 3: iter-1 shortcut. Y0 = M/s; T1 = 1.5I - 0.5*Y0; Z1 = T1.
// ---------------------------------------------------------------------------
__global__ __launch_bounds__(256) void init2_k(const float* __restrict__ M,
                                               const unsigned* __restrict__ sMax,
                                               float* __restrict__ Y0,
                                               float* __restrict__ T,
                                               float* __restrict__ Z1) {
  const float inv = 1.0f / __uint_as_float(*sMax);
  const int i0 = (blockIdx.x * 256 + threadIdx.x) * 4;
  const float4 m4 = *(const float4*)&M[i0];
  const int row = i0 >> 9, col0 = i0 & 511;
  float y[4], tv[4];
#pragma unroll
  for (int e = 0; e < 4; ++e) {
    y[e] = (&m4.x)[e] * inv;
    tv[e] = (row == col0 + e ? 1.5f : 0.f) - 0.5f * y[e];
  }
  *(float4*)&Y0[i0] = make_float4(y[0], y[1], y[2], y[3]);
  const float4 t4 = make_float4(tv[0], tv[1], tv[2], tv[3]);
  *(float4*)&T[i0] = t4;
  *(float4*)&Z1[i0] = t4;
}

// ---------------------------------------------------------------------------
// 512x512x512 fp32 matmul body (32x32 tile / block, 2x2 per thread)
// ---------------------------------------------------------------------------
__device__ __forceinline__ void mm512_body(const float* __restrict__ A,
                                           const float* __restrict__ B,
                                           float* a00, float* a01, float* a10,
                                           float* a11, int rbase, int cbase) {
  __shared__ float As[32][36];
  __shared__ float Bs[32][36];
  const int t = threadIdx.x;
  const int tx = t & 15, ty = t >> 4;
  const int sr = t >> 3, sc = (t & 7) * 4;
  float c00 = 0.f, c01 = 0.f, c10 = 0.f, c11 = 0.f;
  for (int k0 = 0; k0 < D; k0 += 32) {
    __syncthreads();
    *(float4*)&As[sr][sc] = *(const float4*)(A + (size_t)(rbase + sr) * D + k0 + sc);
    *(float4*)&Bs[sr][sc] = *(const float4*)(B + (size_t)(k0 + sr) * D + cbase + sc);
    __syncthreads();
#pragma unroll
    for (int kk = 0; kk < 32; ++kk) {
      const float av0 = As[2 * ty][kk], av1 = As[2 * ty + 1][kk];
      const float2 bv = *(const float2*)&Bs[kk][2 * tx];
      c00 = fmaf(av0, bv.x, c00);
      c01 = fmaf(av0, bv.y, c01);
      c10 = fmaf(av1, bv.x, c10);
      c11 = fmaf(av1, bv.y, c11);
    }
  }
  *a00 = c00; *a01 = c01; *a10 = c10; *a11 = c11;
}

// O = A @ B (plain store)
__global__ __launch_bounds__(256) void mmY_k(const float* __restrict__ A,
                                             const float* __restrict__ B,
                                             float* __restrict__ O) {
  const int rbase = blockIdx.y * 32, cbase = blockIdx.x * 32;
  float a00, a01, a10, a11;
  mm512_body(A, B, &a00, &a01, &a10, &a11, rbase, cbase);
  const int tx = threadIdx.x & 15, ty = threadIdx.x >> 4;
  const int r0 = rbase + 2 * ty, c0 = cbase + 2 * tx;
  O[(size_t)r0 * D + c0] = a00;
  O[(size_t)r0 * D + c0 + 1] = a01;
  O[(size_t)(r0 + 1) * D + c0] = a10;
  O[(size_t)(r0 + 1) * D + c0 + 1] = a11;
}

// T = 1.5 I - 0.5 * (Z @ Y)
__global__ __launch_bounds__(256) void mmT_k(const float* __restrict__ Zm,
                                             const float* __restrict__ Ym,
                                             float* __restrict__ T) {
  const int rbase = blockIdx.y * 32, cbase = blockIdx.x * 32;
  float a00, a01, a10, a11;
  mm512_body(Zm, Ym, &a00, &a01, &a10, &a11, rbase, cbase);
  const int tx = threadIdx.x & 15, ty = threadIdx.x >> 4;
  const int r0 = rbase + 2 * ty, c0 = cbase + 2 * tx;
  T[(size_t)r0 * D + c0] = (r0 == c0 ? 1.5f : 0.f) - 0.5f * a00;
  T[(size_t)r0 * D + c0 + 1] = (r0 == c0 + 1 ? 1.5f : 0.f) - 0.5f * a01;
  T[(size_t)(r0 + 1) * D + c0] = (r0 + 1 == c0 ? 1.5f : 0.f) - 0.5f * a10;
  T[(size_t)(r0 + 1) * D + c0 + 1] = (r0 + 1 == c0 + 1 ? 1.5f : 0.f) - 0.5f * a11;
}

// z=0: Ynew = Y @ T ; z=1: Znew = T @ Z
__global__ __launch_bounds__(256) void mmpair_k(const float* __restrict__ Y,
                                                const float* __restrict__ Z,
                                                const float* __restrict__ T,
                                                float* __restrict__ Yn,
                                                float* __restrict__ Zn) {
  const float* A = blockIdx.z ? T : Y;
  const float* B = blockIdx.z ? Z : T;
  float* O = blockIdx.z ? Zn : Yn;
  const int rbase = blockIdx.y * 32, cbase = blockIdx.x * 32;
  float a00, a01, a10, a11;
  mm512_body(A, B, &a00, &a01, &a10, &a11, rbase, cbase);
  const int tx = threadIdx.x & 15, ty = threadIdx.x >> 4;
  const int r0 = rbase + 2 * ty, c0 = cbase + 2 * tx;
  O[(size_t)r0 * D + c0] = a00;
  O[(size_t)r0 * D + c0 + 1] = a01;
  O[(size_t)(r0 + 1) * D + c0] = a10;
  O[(size_t)(r0 + 1) * D + c0 + 1] = a11;
}

// ---------------------------------------------------------------------------
// Kernel 4 (final NS iter, fused): Zfinal = T @ Z, written as pre-swizzled
// bf16 panels (BK=32 layout) scaled by 1/sqrt(s).
// panel layout: [nb(4)][ks(16)][nl(128)][ch'(4)][e(8)] bf16 (512 KB)
// ---------------------------------------------------------------------------
__global__ __launch_bounds__(256) void mmZp_k(const float* __restrict__ T,
                                              const float* __restrict__ Z,
                                              const unsigned* __restrict__ sMax,
                                              short* __restrict__ panels) {
  const int rbase = blockIdx.y * 32, cbase = blockIdx.x * 32;
  float a00, a01, a10, a11;
  mm512_body(T, Z, &a00, &a01, &a10, &a11, rbase, cbase);
  const float rs = rsqrtf(__uint_as_float(*sMax));
  const int tx = threadIdx.x & 15, ty = threadIdx.x >> 4;
  const int r0 = rbase + 2 * ty, c0 = cbase + 2 * tx;
  const float vv[2][2] = {{a00, a01}, {a10, a11}};
#pragma unroll
  for (int dr = 0; dr < 2; ++dr)
#pragma unroll
    for (int dc = 0; dc < 2; ++dc) {
      const int k = r0 + dr, n = c0 + dc;
      const int nb_ = n >> 7, nl = n & 127;
      const int ks = k >> 5, kl = k & 31;
      const int ch = (kl >> 3) ^ ((nl >> 1) & 3), e = kl & 7;
      const size_t pi = (size_t)((nb_ * 16 + ks) * 128 + nl) * 32 + ch * 8 + e;
      panels[pi] = (short)f2bf(vv[dr][dc] * rs);
    }
}

// ---------------------------------------------------------------------------
// Kernel 5 (r12, kept): out = x @ B. grid 8192, 256 thr, BK=32, 32KB LDS,
// 2-deep counted-vmcnt DMA pipeline, GSW both-sides swizzle.
// ---------------------------------------------------------------------------
__global__ __launch_bounds__(256) void gemm_k(const short* __restrict__ xb16,
                                              const short* __restrict__ panels,
                                              float* __restrict__ out) {
  __shared__ short lds[4][128 * 32];  // [0,1]=A dbuf, [2,3]=B dbuf (32 KB)

  const int hw = blockIdx.x;
  const int q = hw & 7, j = hw >> 3;
  const int ct = j & 3;
  const int rp = ((j >> 2) << 3) | q;
  const size_t rbase = (size_t)rp * 128;

  const int tid = threadIdx.x;
  const int lane = tid & 63, wave = tid >> 6;
  const int wr = wave >> 1, wc = wave & 1;
  const int l15 = lane & 15, g = lane >> 4;

  f32x4 acc[4][4];
#pragma unroll
  for (int i = 0; i < 4; ++i)
#pragma unroll
    for (int j2 = 0; j2 < 4; ++j2) acc[i][j2] = f32x4{0.f, 0.f, 0.f, 0.f};

  auto STAGE = [&](int buf, int ksv) {
#pragma unroll
    for (int i = 0; i < 2; ++i) {
      const int rowbase = wave * 32 + i * 16;
      const int m = rowbase + (lane >> 2);
      const short* src =
          xb16 + (rbase + m) * D + ksv * 32 + GSW(m, lane & 3);
      gld_lds16(src, &lds[buf][rowbase * 32]);
    }
    const short* srcB = panels + ((size_t)(ct * 16 + ksv) << 12);
#pragma unroll
    for (int i = 0; i < 2; ++i)
      gld_lds16(srcB + wave * 1024 + i * 512 + lane * 8,
                &lds[2 + buf][wave * 1024 + i * 512]);
  };

  STAGE(0, 0);  // prologue

  for (int ks = 0; ks < 16; ++ks) {
    const int cur = ks & 1;
    if (ks < 15) {
      STAGE(cur ^ 1, ks + 1);
      asm volatile("s_waitcnt vmcnt(4)" ::: "memory");
    } else {
      asm volatile("s_waitcnt vmcnt(0)" ::: "memory");
    }
    __builtin_amdgcn_s_barrier();
    __builtin_amdgcn_sched_barrier(0);

    const short* rA = lds[cur];
    const short* rB = lds[2 + cur];
    s16x8 af[4], bfv[4];
#pragma unroll
    for (int mi = 0; mi < 4; ++mi) {
      const int m = 64 * wr + 16 * mi + l15;
      af[mi] = *(const s16x8*)(rA + m * 32 + GSW(m, g));
    }
#pragma unroll
    for (int nj = 0; nj < 4; ++nj) {
      const int n = 64 * wc + 16 * nj + l15;
      bfv[nj] = *(const s16x8*)(rB + n * 32 + GSW(n, g));
    }
#pragma unroll
    for (int mi = 0; mi < 4; ++mi)
#pragma unroll
      for (int nj = 0; nj < 4; ++nj)
        acc[mi][nj] = mfma16(af[mi], bfv[nj], acc[mi][nj]);

    asm volatile("s_waitcnt lgkmcnt(0)" ::: "memory");
    __builtin_amdgcn_s_barrier();
    __builtin_amdgcn_sched_barrier(0);
  }

  // epilogue: per-wave transpose through LDS, contiguous float4 NT stores
  float* scratch = (float*)&lds[0][0];
  const int wbase = wave * 1088;
#pragma unroll
  for (int mi = 0; mi < 4; ++mi) {
#pragma unroll
    for (int nj = 0; nj < 4; ++nj)
#pragma unroll
      for (int r = 0; r < 4; ++r)
        scratch[wbase + (4 * g + r) * 68 + 16 * nj + l15] = acc[mi][nj][r];
    __syncthreads();
#pragma unroll
    for (int i = 0; i < 4; ++i) {
      const int rl = g + 4 * i;
      const f32x4 v = *(const f32x4*)&scratch[wbase + rl * 68 + l15 * 4];
      const size_t row_g = rbase + 64 * wr + 16 * mi + rl;
      const int col_g = ct * 128 + 64 * wc + l15 * 4;
      __builtin_nontemporal_store(v, (f32x4*)(out + row_g * D + col_g));
    }
    __syncthreads();
  }
}

// ---------------------------------------------------------------------------
// Fallback (ws too small for xb16): A from fp32 x with f2bf, BK=32 layout.
// ---------------------------------------------------------------------------
__global__ __launch_bounds__(256) void gemm_fb_k(const float* __restrict__ x,
                                                 const short* __restrict__ panels,
                                                 float* __restrict__ out) {
  __shared__ short lds[2][128 * 32];

  const int hw = blockIdx.x;
  const int q = hw & 7, j = hw >> 3;
  const int ct = j & 3;
  const int rp = ((j >> 2) << 3) | q;
  const size_t rbase = (size_t)rp * 128;

  const int tid = threadIdx.x;
  const int lane = tid & 63, wave = tid >> 6;
  const int wr = wave >> 1, wc = wave & 1;
  const int l15 = lane & 15, g = lane >> 4;

  const int am = tid >> 1;
  const int ak0 = (tid & 1) * 16;

  f32x4 acc[4][4];
#pragma unroll
  for (int i = 0; i < 4; ++i)
#pragma unroll
    for (int j2 = 0; j2 < 4; ++j2) acc[i][j2] = f32x4{0.f, 0.f, 0.f, 0.f};

  for (int ks = 0; ks < 16; ++ks) {
    __syncthreads();
    {
      s16x8 p;
#pragma unroll
      for (int h = 0; h < 2; ++h) {
        const float4 a =
            *(const float4*)(x + (rbase + am) * D + ks * 32 + ak0 + h * 8);
        const float4 b =
            *(const float4*)(x + (rbase + am) * D + ks * 32 + ak0 + h * 8 + 4);
        p[0] = (short)f2bf(a.x); p[1] = (short)f2bf(a.y);
        p[2] = (short)f2bf(a.z); p[3] = (short)f2bf(a.w);
        p[4] = (short)f2bf(b.x); p[5] = (short)f2bf(b.y);
        p[6] = (short)f2bf(b.z); p[7] = (short)f2bf(b.w);
        const int ch = (ak0 >> 3) + h;
        *(s16x8*)(&lds[0][am * 32] + GSW(am, ch)) = p;
      }
    }
    {
      const short* srcB = panels + ((size_t)(ct * 16 + ks) << 12);
#pragma unroll
      for (int i = 0; i < 2; ++i)
        gld_lds16(srcB + wave * 1024 + i * 512 + lane * 8,
                  &lds[1][wave * 1024 + i * 512]);
    }
    __syncthreads();

    s16x8 af[4], bfv[4];
#pragma unroll
    for (int mi = 0; mi < 4; ++mi) {
      const int m = 64 * wr + 16 * mi + l15;
      af[mi] = *(const s16x8*)(&lds[0][m * 32] + GSW(m, g));
    }
#pragma unroll
    for (int nj = 0; nj < 4; ++nj) {
      const int n = 64 * wc + 16 * nj + l15;
      bfv[nj] = *(const s16x8*)(&lds[1][n * 32] + GSW(n, g));
    }
#pragma unroll
    for (int mi = 0; mi < 4; ++mi)
#pragma unroll
      for (int nj = 0; nj < 4; ++nj)
        acc[mi][nj] = mfma16(af[mi], bfv[nj], acc[mi][nj]);
  }

  __syncthreads();
  float* scratch = (float*)&lds[0][0];
  const int wbase = wave * 1088;
#pragma unroll
  for (int mi = 0; mi < 4; ++mi) {
#pragma unroll
    for (int nj = 0; nj < 4; ++nj)
#pragma unroll
      for (int r = 0; r < 4; ++r)
        scratch[wbase + (4 * g + r) * 68 + 16 * nj + l15] = acc[mi][nj][r];
    __syncthreads();
#pragma unroll
    for (int i = 0; i < 4; ++i) {
      const int rl = g + 4 * i;
      const f32x4 v = *(const f32x4*)&scratch[wbase + rl * 68 + l15 * 4];
      const size_t row_g = rbase + 64 * wr + 16 * mi + rl;
      const int col_g = ct * 128 + 64 * wc + l15 * 4;
      __builtin_nontemporal_store(v, (f32x4*)(out + row_g * D + col_g));
    }
    __syncthreads();
  }
}

// ---------------------------------------------------------------------------
extern "C" void kernel_launch(void* const* d_in, const int* in_sizes, int n_in,
                              void* d_out, int out_size, void* d_ws,
                              size_t ws_size, hipStream_t stream) {
  (void)in_sizes; (void)n_in; (void)out_size;
  const float* x = (const float*)d_in[0];
  const float* run = (const float*)d_in[1];
  float* out = (float*)d_out;
  uint8_t* ws = (uint8_t*)d_ws;

  float* Cpart = (float*)ws;                          // 8 MB (8 x 1MB)
  unsigned* sMax = (unsigned*)(ws + (8u << 20));      // 256 B slot
  float* M = (float*)(ws + (8u << 20) + 256);         // 1 MB
  float* Ya = M + 262144;
  float* Yb = Ya + 262144;
  float* Za = Yb + 262144;
  float* Zb = Za + 262144;
  float* T = Zb + 262144;
  short* panels = (short*)(T + 262144);               // 512 KB
  short* xb16 = panels + 262144;                      // 256 MB (optional)

  const size_t need =
      (size_t)((uint8_t*)xb16 - ws) + (size_t)N_ROWS * D * sizeof(short);
  const bool big = ws_size >= need;

  (void)hipMemsetAsync(Cpart, 0, (8u << 20) + 256, stream);

  covar_k<<<768, 1024, 0, stream>>>(x, Cpart, big ? xb16 : nullptr);
  prep_k<<<512, 256, 0, stream>>>(Cpart, run, M, sMax);

  // NS iter 1 (Z0 = I): T1 elementwise, Z1 = T1, Y1 = Y0 @ T1
  init2_k<<<256, 256, 0, stream>>>(M, sMax, Ya, T, Za);
  mmY_k<<<dim3(16, 16), 256, 0, stream>>>(Ya, T, Yb);

  // NS iters 2..NS_ITERS-1 (full coupled)
  float *Y = Yb, *Z = Za, *Yn = Ya, *Zn = Zb;
  for (int it = 1; it < NS_ITERS - 1; ++it) {
    mmT_k<<<dim3(16, 16), 256, 0, stream>>>(Z, Y, T);
    mmpair_k<<<dim3(16, 16, 2), 256, 0, stream>>>(Y, Z, T, Yn, Zn);
    float* t1 = Y; Y = Yn; Yn = t1;
    t1 = Z; Z = Zn; Zn = t1;
  }

  // final NS iter: only Z needed; fused panel build (BK=32 layout)
  mmT_k<<<dim3(16, 16), 256, 0, stream>>>(Z, Y, T);
  mmZp_k<<<dim3(16, 16), 256, 0, stream>>>(T, Z, sMax, panels);

  if (big)
    gemm_k<<<8192, 256, 0, stream>>>(xb16, panels, out);
  else
    gemm_fb_k<<<8192, 256, 0, stream>>>(x, panels, out);
}

// Round 15
// 621.861 us; speedup vs baseline: 1.0092x; 1.0092x over previous
//
#include <hip/hip_runtime.h>
#include <stdint.h>

// ---------------------------------------------------------------------------
// BatchWhiten: out = x @ inv_sqrtm(max(0.1*running + 0.9*(x^T x)/N, 1e-5))
// x: [262144, 512] fp32, running: [512,512] fp32, out: [262144,512] fp32
// r15 = r12 best-known config (561us) + compiler-cast bf16 conversion
// (v_cvt_pk_bf16_f32 fusion) replacing hand-rolled f2bf bit arithmetic.
// ---------------------------------------------------------------------------

#define N_ROWS 262144
#define D 512
#define NS_ITERS 3  // 1 simplified (Z0=I) + 1 full + 1 final Z-only (fused)
#define CK_CHUNKS 128
#define CK_ROWS (N_ROWS / CK_CHUNKS)  // 2048
#define BKC 32
#define CK_STEPS (CK_ROWS / BKC)      // 64

typedef float f32x4 __attribute__((ext_vector_type(4)));
typedef short s16x8 __attribute__((ext_vector_type(8)));
typedef short s16x4 __attribute__((ext_vector_type(4)));
typedef __bf16 bf16x8 __attribute__((ext_vector_type(8)));

// compiler cast: RNE, pairs fuse to v_cvt_pk_bf16_f32 (guide m240: faster
// than hand-written bit arithmetic or inline-asm cvt_pk)
static __device__ __forceinline__ unsigned short f2bf(float f) {
  return __builtin_bit_cast(unsigned short, (__bf16)f);
}

static __device__ __forceinline__ f32x4 mfma16(s16x8 a, s16x8 b, f32x4 c) {
  return __builtin_amdgcn_mfma_f32_16x16x32_bf16(
      __builtin_bit_cast(bf16x8, a), __builtin_bit_cast(bf16x8, b), c, 0, 0, 0);
}

// async global->LDS, 16B per lane; LDS dest = wave-uniform base + lane*16
static __device__ __forceinline__ void gld_lds16(const void* g, void* l) {
  __builtin_amdgcn_global_load_lds(
      (const __attribute__((address_space(1))) void*)g,
      (__attribute__((address_space(3))) void*)l, 16, 0, 0);
}

#define SWZ8(c) (((c) ^ ((c) >> 3)) & 7)

// Conflict-free covar LDS slot map (r11, verified): tile [128 c][32 k] bf16.
#define CVOFF(c, kc) \
  ((((c) >> 1) << 6) + ((((((kc) << 1) | ((c) & 1))) ^ SWZ8((c) >> 1)) << 3))

// BK=32 row swizzle for gemm tiles (rows = 32 shorts = 64B)
#define GSW(row, g) (((g) ^ (((row) >> 1) & 3)) << 3)

// raw barrier, LDS-writes published, NO vmcnt drain
static __device__ __forceinline__ void bar_lgkm() {
  asm volatile("s_waitcnt lgkmcnt(0)" ::: "memory");
  __builtin_amdgcn_s_barrier();
  __builtin_amdgcn_sched_barrier(0);
}

// ---------------------------------------------------------------------------
// Kernel 1 (r11/r12 best): Cpart[xcd] += x^T x. grid 1280 x 512 thr (8
// waves), wave tile 64x32 (acc 32 VGPR), waves 0-3 stage A, 4-7 stage B,
// CVOFF conflict-free slots, reg-prefetch + LDS dbuf + lgkm-only barrier.
// ---------------------------------------------------------------------------
__global__ __launch_bounds__(512) void covar_k(const float* __restrict__ x,
                                               float* __restrict__ Cpart,
                                               short* __restrict__ xb16) {
  __shared__ short ldsT[2][2][128 * 32];  // [dbuf][A,B][tile] = 32 KB

  // bijective XCD swizzle: 1280 works = 8 XCDs x 160
  const int hw = blockIdx.x;
  const int work = (hw & 7) * 160 + (hw >> 3);
  int t = work % 10, mb = 0, rl = 4;
  while (t >= rl) { t -= rl; ++mb; --rl; }
  const int nb = mb + t;
  const int chunk = work / 10;
  float* C = Cpart + (size_t)(hw & 7) * (D * D);

  const int tid = threadIdx.x;
  const int lane = tid & 63;
  const int wave = tid >> 6;   // 0..7
  const int isB = wave >> 2;   // staging role: 0 = A tile, 1 = B tile
  const int kh = wave & 3;     // staged k-chunk (8 rows)
  const int c2 = lane * 2;     // staged column pair

  const int wr = wave >> 2, wc = wave & 3;  // MFMA wave tile 64(m) x 32(n)
  const int l15 = lane & 15, g = lane >> 4;

  const bool offd = (nb != mb);
  const bool doStage = (!isB) || offd;
  const int tileCol = (isB ? nb : mb) * 128;

  const bool haveDump = (xb16 != nullptr);
  const int rank = isB ? (4 - (nb - mb)) : (nb - mb);
  const bool dump = haveDump && doStage && (kh == rank);
  uint32_t* xw = (uint32_t*)xb16;

  f32x4 acc[4][2];
#pragma unroll
  for (int i = 0; i < 4; ++i)
#pragma unroll
    for (int j = 0; j < 2; ++j) acc[i][j] = f32x4{0.f, 0.f, 0.f, 0.f};

  const size_t kbase0 = (size_t)chunk * CK_ROWS;
  const float* srcBase = x + (kbase0 + kh * 8) * D + tileCol + c2;

  float2 buf[8];
  if (doStage) {
#pragma unroll
    for (int q = 0; q < 8; ++q) buf[q] = *(const float2*)(srcBase + (size_t)q * D);
  }

  for (int st = 0; st < CK_STEPS; ++st) {
    if (doStage) {
      s16x8 p0, p1;
#pragma unroll
      for (int q = 0; q < 8; ++q) {
        p0[q] = (short)f2bf(buf[q].x);
        p1[q] = (short)f2bf(buf[q].y);
      }
      if (st + 1 < CK_STEPS) {
        const float* src = srcBase + (size_t)(st + 1) * BKC * D;
#pragma unroll
        for (int q = 0; q < 8; ++q) buf[q] = *(const float2*)(src + (size_t)q * D);
      }
      short* wp = ldsT[st & 1][isB];
      *(s16x8*)(wp + CVOFF(c2, kh)) = p0;
      *(s16x8*)(wp + CVOFF(c2 + 1, kh)) = p1;
      if (dump) {
        const size_t k0 = kbase0 + (size_t)st * BKC;
#pragma unroll
        for (int q = 0; q < 8; ++q) {
          const uint32_t u = (uint32_t)(uint16_t)p0[q] |
                             ((uint32_t)(uint16_t)p1[q] << 16);
          __builtin_nontemporal_store(
              u, &xw[(k0 + kh * 8 + q) * 256 + (tileCol >> 1) + lane]);
        }
      }
    }

    bar_lgkm();  // publish ds_writes; NO vmcnt drain

    const short* rA = ldsT[st & 1][0];
    const short* rB = ldsT[st & 1][offd ? 1 : 0];
    s16x8 af[4], bfv[2];
#pragma unroll
    for (int mi = 0; mi < 4; ++mi) {
      const int m = 64 * wr + 16 * mi + l15;
      af[mi] = *(const s16x8*)(rA + CVOFF(m, g));
    }
#pragma unroll
    for (int nj = 0; nj < 2; ++nj) {
      const int n = 32 * wc + 16 * nj + l15;
      bfv[nj] = *(const s16x8*)(rB + CVOFF(n, g));
    }
#pragma unroll
    for (int mi = 0; mi < 4; ++mi)
#pragma unroll
      for (int nj = 0; nj < 2; ++nj)
        acc[mi][nj] = mfma16(af[mi], bfv[nj], acc[mi][nj]);
  }

  // epilogue: atomic accumulate into this XCD's partial buffer
#pragma unroll
  for (int mi = 0; mi < 4; ++mi)
#pragma unroll
    for (int nj = 0; nj < 2; ++nj) {
      const int n = nb * 128 + 32 * wc + 16 * nj + l15;
#pragma unroll
      for (int r = 0; r < 4; ++r) {
        const int m = mb * 128 + 64 * wr + 16 * mi + 4 * g + r;
        atomicAdd(&C[(size_t)m * D + n], acc[mi][nj][r]);
      }
    }
}

// ---------------------------------------------------------------------------
// Kernel 2: M = max(0.1*run + (0.9/N)*sum_p Cpart[p], 1e-5); sMax = max rowsum
// ---------------------------------------------------------------------------
__global__ __launch_bounds__(256) void prep_k(const float* __restrict__ Cpart,
                                              const float* __restrict__ run,
                                              float* __restrict__ M,
                                              unsigned* __restrict__ sMax) {
  const int r = blockIdx.x;
  const int t = threadIdx.x;
  const float cs = 0.9f / (float)N_ROWS;
  float sum = 0.f;
  for (int c = t; c < D; c += 256) {
    const int rr = r < c ? r : c;
    const int cc = r < c ? c : r;
    float cv = 0.f;
#pragma unroll
    for (int p = 0; p < 8; ++p)
      cv += Cpart[(size_t)p * D * D + (size_t)rr * D + cc];
    float v = 0.1f * run[(size_t)r * D + c] + cs * cv;
    v = fmaxf(v, 1e-5f);
    M[(size_t)r * D + c] = v;
    sum += v;
  }
  __shared__ float red[256];
  red[t] = sum;
  __syncthreads();
  for (int off = 128; off > 0; off >>= 1) {
    if (t < off) red[t] += red[t + off];
    __syncthreads();
  }
  if (t == 0) atomicMax(sMax, __float_as_uint(red[0]));
}

// ---------------------------------------------------------------------------
// Kernel 3: iter-1 shortcut. Y0 = M/s; T1 = 1.5I - 0.5*Y0; Z1 = T1.
// ---------------------------------------------------------------------------
__global__ __launch_bounds__(256) void init2_k(const float* __restrict__ M,
                                               const unsigned* __restrict__ sMax,
                                               float* __restrict__ Y0,
                                               float* __restrict__ T,
                                               float* __restrict__ Z1) {
  const float inv = 1.0f / __uint_as_float(*sMax);
  const int i0 = (blockIdx.x * 256 + threadIdx.x) * 4;
  const float4 m4 = *(const float4*)&M[i0];
  const int row = i0 >> 9, col0 = i0 & 511;
  float y[4], tv[4];
#pragma unroll
  for (int e = 0; e < 4; ++e) {
    y[e] = (&m4.x)[e] * inv;
    tv[e] = (row == col0 + e ? 1.5f : 0.f) - 0.5f * y[e];
  }
  *(float4*)&Y0[i0] = make_float4(y[0], y[1], y[2], y[3]);
  const float4 t4 = make_float4(tv[0], tv[1], tv[2], tv[3]);
  *(float4*)&T[i0] = t4;
  *(float4*)&Z1[i0] = t4;
}

// ---------------------------------------------------------------------------
// 512x512x512 fp32 matmul body (32x32 tile / block, 2x2 per thread)
// ---------------------------------------------------------------------------
__device__ __forceinline__ void mm512_body(const float* __restrict__ A,
                                           const float* __restrict__ B,
                                           float* a00, float* a01, float* a10,
                                           float* a11, int rbase, int cbase) {
  __shared__ float As[32][36];
  __shared__ float Bs[32][36];
  const int t = threadIdx.x;
  const int tx = t & 15, ty = t >> 4;
  const int sr = t >> 3, sc = (t & 7) * 4;
  float c00 = 0.f, c01 = 0.f, c10 = 0.f, c11 = 0.f;
  for (int k0 = 0; k0 < D; k0 += 32) {
    __syncthreads();
    *(float4*)&As[sr][sc] = *(const float4*)(A + (size_t)(rbase + sr) * D + k0 + sc);
    *(float4*)&Bs[sr][sc] = *(const float4*)(B + (size_t)(k0 + sr) * D + cbase + sc);
    __syncthreads();
#pragma unroll
    for (int kk = 0; kk < 32; ++kk) {
      const float av0 = As[2 * ty][kk], av1 = As[2 * ty + 1][kk];
      const float2 bv = *(const float2*)&Bs[kk][2 * tx];
      c00 = fmaf(av0, bv.x, c00);
      c01 = fmaf(av0, bv.y, c01);
      c10 = fmaf(av1, bv.x, c10);
      c11 = fmaf(av1, bv.y, c11);
    }
  }
  *a00 = c00; *a01 = c01; *a10 = c10; *a11 = c11;
}

// O = A @ B (plain store)
__global__ __launch_bounds__(256) void mmY_k(const float* __restrict__ A,
                                             const float* __restrict__ B,
                                             float* __restrict__ O) {
  const int rbase = blockIdx.y * 32, cbase = blockIdx.x * 32;
  float a00, a01, a10, a11;
  mm512_body(A, B, &a00, &a01, &a10, &a11, rbase, cbase);
  const int tx = threadIdx.x & 15, ty = threadIdx.x >> 4;
  const int r0 = rbase + 2 * ty, c0 = cbase + 2 * tx;
  O[(size_t)r0 * D + c0] = a00;
  O[(size_t)r0 * D + c0 + 1] = a01;
  O[(size_t)(r0 + 1) * D + c0] = a10;
  O[(size_t)(r0 + 1) * D + c0 + 1] = a11;
}

// T = 1.5 I - 0.5 * (Z @ Y)
__global__ __launch_bounds__(256) void mmT_k(const float* __restrict__ Zm,
                                             const float* __restrict__ Ym,
                                             float* __restrict__ T) {
  const int rbase = blockIdx.y * 32, cbase = blockIdx.x * 32;
  float a00, a01, a10, a11;
  mm512_body(Zm, Ym, &a00, &a01, &a10, &a11, rbase, cbase);
  const int tx = threadIdx.x & 15, ty = threadIdx.x >> 4;
  const int r0 = rbase + 2 * ty, c0 = cbase + 2 * tx;
  T[(size_t)r0 * D + c0] = (r0 == c0 ? 1.5f : 0.f) - 0.5f * a00;
  T[(size_t)r0 * D + c0 + 1] = (r0 == c0 + 1 ? 1.5f : 0.f) - 0.5f * a01;
  T[(size_t)(r0 + 1) * D + c0] = (r0 + 1 == c0 ? 1.5f : 0.f) - 0.5f * a10;
  T[(size_t)(r0 + 1) * D + c0 + 1] = (r0 + 1 == c0 + 1 ? 1.5f : 0.f) - 0.5f * a11;
}

// z=0: Ynew = Y @ T ; z=1: Znew = T @ Z
__global__ __launch_bounds__(256) void mmpair_k(const float* __restrict__ Y,
                                                const float* __restrict__ Z,
                                                const float* __restrict__ T,
                                                float* __restrict__ Yn,
                                                float* __restrict__ Zn) {
  const float* A = blockIdx.z ? T : Y;
  const float* B = blockIdx.z ? Z : T;
  float* O = blockIdx.z ? Zn : Yn;
  const int rbase = blockIdx.y * 32, cbase = blockIdx.x * 32;
  float a00, a01, a10, a11;
  mm512_body(A, B, &a00, &a01, &a10, &a11, rbase, cbase);
  const int tx = threadIdx.x & 15, ty = threadIdx.x >> 4;
  const int r0 = rbase + 2 * ty, c0 = cbase + 2 * tx;
  O[(size_t)r0 * D + c0] = a00;
  O[(size_t)r0 * D + c0 + 1] = a01;
  O[(size_t)(r0 + 1) * D + c0] = a10;
  O[(size_t)(r0 + 1) * D + c0 + 1] = a11;
}

// ---------------------------------------------------------------------------
// Kernel 4 (final NS iter, fused): Zfinal = T @ Z, written as pre-swizzled
// bf16 panels (BK=32 layout) scaled by 1/sqrt(s).
// panel layout: [nb(4)][ks(16)][nl(128)][ch'(4)][e(8)] bf16 (512 KB)
// ---------------------------------------------------------------------------
__global__ __launch_bounds__(256) void mmZp_k(const float* __restrict__ T,
                                              const float* __restrict__ Z,
                                              const unsigned* __restrict__ sMax,
                                              short* __restrict__ panels) {
  const int rbase = blockIdx.y * 32, cbase = blockIdx.x * 32;
  float a00, a01, a10, a11;
  mm512_body(T, Z, &a00, &a01, &a10, &a11, rbase, cbase);
  const float rs = rsqrtf(__uint_as_float(*sMax));
  const int tx = threadIdx.x & 15, ty = threadIdx.x >> 4;
  const int r0 = rbase + 2 * ty, c0 = cbase + 2 * tx;
  const float vv[2][2] = {{a00, a01}, {a10, a11}};
#pragma unroll
  for (int dr = 0; dr < 2; ++dr)
#pragma unroll
    for (int dc = 0; dc < 2; ++dc) {
      const int k = r0 + dr, n = c0 + dc;
      const int nb_ = n >> 7, nl = n & 127;
      const int ks = k >> 5, kl = k & 31;
      const int ch = (kl >> 3) ^ ((nl >> 1) & 3), e = kl & 7;
      const size_t pi = (size_t)((nb_ * 16 + ks) * 128 + nl) * 32 + ch * 8 + e;
      panels[pi] = (short)f2bf(vv[dr][dc] * rs);
    }
}

// ---------------------------------------------------------------------------
// Kernel 5 (r12): out = x @ B. grid 8192, 256 thr, BK=32, 32KB LDS,
// 2-deep counted-vmcnt DMA pipeline, GSW both-sides swizzle.
// ---------------------------------------------------------------------------
__global__ __launch_bounds__(256) void gemm_k(const short* __restrict__ xb16,
                                              const short* __restrict__ panels,
                                              float* __restrict__ out) {
  __shared__ short lds[4][128 * 32];  // [0,1]=A dbuf, [2,3]=B dbuf (32 KB)

  const int hw = blockIdx.x;
  const int q = hw & 7, j = hw >> 3;
  const int ct = j & 3;
  const int rp = ((j >> 2) << 3) | q;
  const size_t rbase = (size_t)rp * 128;

  const int tid = threadIdx.x;
  const int lane = tid & 63, wave = tid >> 6;
  const int wr = wave >> 1, wc = wave & 1;
  const int l15 = lane & 15, g = lane >> 4;

  f32x4 acc[4][4];
#pragma unroll
  for (int i = 0; i < 4; ++i)
#pragma unroll
    for (int j2 = 0; j2 < 4; ++j2) acc[i][j2] = f32x4{0.f, 0.f, 0.f, 0.f};

  auto STAGE = [&](int buf, int ksv) {
#pragma unroll
    for (int i = 0; i < 2; ++i) {
      const int rowbase = wave * 32 + i * 16;
      const int m = rowbase + (lane >> 2);
      const short* src =
          xb16 + (rbase + m) * D + ksv * 32 + GSW(m, lane & 3);
      gld_lds16(src, &lds[buf][rowbase * 32]);
    }
    const short* srcB = panels + ((size_t)(ct * 16 + ksv) << 12);
#pragma unroll
    for (int i = 0; i < 2; ++i)
      gld_lds16(srcB + wave * 1024 + i * 512 + lane * 8,
                &lds[2 + buf][wave * 1024 + i * 512]);
  };

  STAGE(0, 0);  // prologue

  for (int ks = 0; ks < 16; ++ks) {
    const int cur = ks & 1;
    if (ks < 15) {
      STAGE(cur ^ 1, ks + 1);
      asm volatile("s_waitcnt vmcnt(4)" ::: "memory");
    } else {
      asm volatile("s_waitcnt vmcnt(0)" ::: "memory");
    }
    __builtin_amdgcn_s_barrier();
    __builtin_amdgcn_sched_barrier(0);

    const short* rA = lds[cur];
    const short* rB = lds[2 + cur];
    s16x8 af[4], bfv[4];
#pragma unroll
    for (int mi = 0; mi < 4; ++mi) {
      const int m = 64 * wr + 16 * mi + l15;
      af[mi] = *(const s16x8*)(rA + m * 32 + GSW(m, g));
    }
#pragma unroll
    for (int nj = 0; nj < 4; ++nj) {
      const int n = 64 * wc + 16 * nj + l15;
      bfv[nj] = *(const s16x8*)(rB + n * 32 + GSW(n, g));
    }
#pragma unroll
    for (int mi = 0; mi < 4; ++mi)
#pragma unroll
      for (int nj = 0; nj < 4; ++nj)
        acc[mi][nj] = mfma16(af[mi], bfv[nj], acc[mi][nj]);

    asm volatile("s_waitcnt lgkmcnt(0)" ::: "memory");
    __builtin_amdgcn_s_barrier();
    __builtin_amdgcn_sched_barrier(0);
  }

  // epilogue: per-wave transpose through LDS, contiguous float4 NT stores
  float* scratch = (float*)&lds[0][0];
  const int wbase = wave * 1088;
#pragma unroll
  for (int mi = 0; mi < 4; ++mi) {
#pragma unroll
    for (int nj = 0; nj < 4; ++nj)
#pragma unroll
      for (int r = 0; r < 4; ++r)
        scratch[wbase + (4 * g + r) * 68 + 16 * nj + l15] = acc[mi][nj][r];
    __syncthreads();
#pragma unroll
    for (int i = 0; i < 4; ++i) {
      const int rl = g + 4 * i;
      const f32x4 v = *(const f32x4*)&scratch[wbase + rl * 68 + l15 * 4];
      const size_t row_g = rbase + 64 * wr + 16 * mi + rl;
      const int col_g = ct * 128 + 64 * wc + l15 * 4;
      __builtin_nontemporal_store(v, (f32x4*)(out + row_g * D + col_g));
    }
    __syncthreads();
  }
}

// ---------------------------------------------------------------------------
// Fallback (ws too small for xb16): A from fp32 x with f2bf, BK=32 layout.
// ---------------------------------------------------------------------------
__global__ __launch_bounds__(256) void gemm_fb_k(const float* __restrict__ x,
                                                 const short* __restrict__ panels,
                                                 float* __restrict__ out) {
  __shared__ short lds[2][128 * 32];

  const int hw = blockIdx.x;
  const int q = hw & 7, j = hw >> 3;
  const int ct = j & 3;
  const int rp = ((j >> 2) << 3) | q;
  const size_t rbase = (size_t)rp * 128;

  const int tid = threadIdx.x;
  const int lane = tid & 63, wave = tid >> 6;
  const int wr = wave >> 1, wc = wave & 1;
  const int l15 = lane & 15, g = lane >> 4;

  const int am = tid >> 1;
  const int ak0 = (tid & 1) * 16;

  f32x4 acc[4][4];
#pragma unroll
  for (int i = 0; i < 4; ++i)
#pragma unroll
    for (int j2 = 0; j2 < 4; ++j2) acc[i][j2] = f32x4{0.f, 0.f, 0.f, 0.f};

  for (int ks = 0; ks < 16; ++ks) {
    __syncthreads();
    {
      s16x8 p;
#pragma unroll
      for (int h = 0; h < 2; ++h) {
        const float4 a =
            *(const float4*)(x + (rbase + am) * D + ks * 32 + ak0 + h * 8);
        const float4 b =
            *(const float4*)(x + (rbase + am) * D + ks * 32 + ak0 + h * 8 + 4);
        p[0] = (short)f2bf(a.x); p[1] = (short)f2bf(a.y);
        p[2] = (short)f2bf(a.z); p[3] = (short)f2bf(a.w);
        p[4] = (short)f2bf(b.x); p[5] = (short)f2bf(b.y);
        p[6] = (short)f2bf(b.z); p[7] = (short)f2bf(b.w);
        const int ch = (ak0 >> 3) + h;
        *(s16x8*)(&lds[0][am * 32] + GSW(am, ch)) = p;
      }
    }
    {
      const short* srcB = panels + ((size_t)(ct * 16 + ks) << 12);
#pragma unroll
      for (int i = 0; i < 2; ++i)
        gld_lds16(srcB + wave * 1024 + i * 512 + lane * 8,
                  &lds[1][wave * 1024 + i * 512]);
    }
    __syncthreads();

    s16x8 af[4], bfv[4];
#pragma unroll
    for (int mi = 0; mi < 4; ++mi) {
      const int m = 64 * wr + 16 * mi + l15;
      af[mi] = *(const s16x8*)(&lds[0][m * 32] + GSW(m, g));
    }
#pragma unroll
    for (int nj = 0; nj < 4; ++nj) {
      const int n = 64 * wc + 16 * nj + l15;
      bfv[nj] = *(const s16x8*)(&lds[1][n * 32] + GSW(n, g));
    }
#pragma unroll
    for (int mi = 0; mi < 4; ++mi)
#pragma unroll
      for (int nj = 0; nj < 4; ++nj)
        acc[mi][nj] = mfma16(af[mi], bfv[nj], acc[mi][nj]);
  }

  __syncthreads();
  float* scratch = (float*)&lds[0][0];
  const int wbase = wave * 1088;
#pragma unroll
  for (int mi = 0; mi < 4; ++mi) {
#pragma unroll
    for (int nj = 0; nj < 4; ++nj)
#pragma unroll
      for (int r = 0; r < 4; ++r)
        scratch[wbase + (4 * g + r) * 68 + 16 * nj + l15] = acc[mi][nj][r];
    __syncthreads();
#pragma unroll
    for (int i = 0; i < 4; ++i) {
      const int rl = g + 4 * i;
      const f32x4 v = *(const f32x4*)&scratch[wbase + rl * 68 + l15 * 4];
      const size_t row_g = rbase + 64 * wr + 16 * mi + rl;
      const int col_g = ct * 128 + 64 * wc + l15 * 4;
      __builtin_nontemporal_store(v, (f32x4*)(out + row_g * D + col_g));
    }
    __syncthreads();
  }
}

// ---------------------------------------------------------------------------
extern "C" void kernel_launch(void* const* d_in, const int* in_sizes, int n_in,
                              void* d_out, int out_size, void* d_ws,
                              size_t ws_size, hipStream_t stream) {
  (void)in_sizes; (void)n_in; (void)out_size;
  const float* x = (const float*)d_in[0];
  const float* run = (const float*)d_in[1];
  float* out = (float*)d_out;
  uint8_t* ws = (uint8_t*)d_ws;

  float* Cpart = (float*)ws;                          // 8 MB (8 x 1MB)
  unsigned* sMax = (unsigned*)(ws + (8u << 20));      // 256 B slot
  float* M = (float*)(ws + (8u << 20) + 256);         // 1 MB
  float* Ya = M + 262144;
  float* Yb = Ya + 262144;
  float* Za = Yb + 262144;
  float* Zb = Za + 262144;
  float* T = Zb + 262144;
  short* panels = (short*)(T + 262144);               // 512 KB
  short* xb16 = panels + 262144;                      // 256 MB (optional)

  const size_t need =
      (size_t)((uint8_t*)xb16 - ws) + (size_t)N_ROWS * D * sizeof(short);
  const bool big = ws_size >= need;

  (void)hipMemsetAsync(Cpart, 0, (8u << 20) + 256, stream);

  covar_k<<<1280, 512, 0, stream>>>(x, Cpart, big ? xb16 : nullptr);
  prep_k<<<512, 256, 0, stream>>>(Cpart, run, M, sMax);

  // NS iter 1 (Z0 = I): T1 elementwise, Z1 = T1, Y1 = Y0 @ T1
  init2_k<<<256, 256, 0, stream>>>(M, sMax, Ya, T, Za);
  mmY_k<<<dim3(16, 16), 256, 0, stream>>>(Ya, T, Yb);

  // NS iters 2..NS_ITERS-1 (full coupled)
  float *Y = Yb, *Z = Za, *Yn = Ya, *Zn = Zb;
  for (int it = 1; it < NS_ITERS - 1; ++it) {
    mmT_k<<<dim3(16, 16), 256, 0, stream>>>(Z, Y, T);
    mmpair_k<<<dim3(16, 16, 2), 256, 0, stream>>>(Y, Z, T, Yn, Zn);
    float* t1 = Y; Y = Yn; Yn = t1;
    t1 = Z; Z = Zn; Zn = t1;
  }

  // final NS iter: only Z needed; fused panel build (BK=32 layout)
  mmT_k<<<dim3(16, 16), 256, 0, stream>>>(Z, Y, T);
  mmZp_k<<<dim3(16, 16), 256, 0, stream>>>(T, Z, sMax, panels);

  if (big)
    gemm_k<<<8192, 256, 0, stream>>>(xb16, panels, out);
  else
    gemm_fb_k<<<8192, 256, 0, stream>>>(x, panels, out);
}

// Round 16
// 563.030 us; speedup vs baseline: 1.1147x; 1.1045x over previous
//
#include <hip/hip_runtime.h>
#include <stdint.h>

// ---------------------------------------------------------------------------
// BatchWhiten: out = x @ inv_sqrtm(max(0.1*running + 0.9*(x^T x)/N, 1e-5))
// x: [262144, 512] fp32, running: [512,512] fp32, out: [262144,512] fp32
// r16 = exact revert to r12 best-known config (561.75 us).
// ---------------------------------------------------------------------------

#define N_ROWS 262144
#define D 512
#define NS_ITERS 3  // 1 simplified (Z0=I) + 1 full + 1 final Z-only (fused)
#define CK_CHUNKS 128
#define CK_ROWS (N_ROWS / CK_CHUNKS)  // 2048
#define BKC 32
#define CK_STEPS (CK_ROWS / BKC)      // 64

typedef float f32x4 __attribute__((ext_vector_type(4)));
typedef short s16x8 __attribute__((ext_vector_type(8)));
typedef short s16x4 __attribute__((ext_vector_type(4)));
typedef __bf16 bf16x8 __attribute__((ext_vector_type(8)));

static __device__ __forceinline__ unsigned short f2bf(float f) {
  unsigned u = __float_as_uint(f);
  u += 0x7FFFu + ((u >> 16) & 1u);  // RNE
  return (unsigned short)(u >> 16);
}

static __device__ __forceinline__ f32x4 mfma16(s16x8 a, s16x8 b, f32x4 c) {
  return __builtin_amdgcn_mfma_f32_16x16x32_bf16(
      __builtin_bit_cast(bf16x8, a), __builtin_bit_cast(bf16x8, b), c, 0, 0, 0);
}

// async global->LDS, 16B per lane; LDS dest = wave-uniform base + lane*16
static __device__ __forceinline__ void gld_lds16(const void* g, void* l) {
  __builtin_amdgcn_global_load_lds(
      (const __attribute__((address_space(1))) void*)g,
      (__attribute__((address_space(3))) void*)l, 16, 0, 0);
}

#define SWZ8(c) (((c) ^ ((c) >> 3)) & 7)

// Conflict-free covar LDS slot map (r11, verified): tile [128 c][32 k] bf16.
#define CVOFF(c, kc) \
  ((((c) >> 1) << 6) + ((((((kc) << 1) | ((c) & 1))) ^ SWZ8((c) >> 1)) << 3))

// BK=32 row swizzle for gemm tiles (rows = 32 shorts = 64B)
#define GSW(row, g) (((g) ^ (((row) >> 1) & 3)) << 3)

// raw barrier, LDS-writes published, NO vmcnt drain
static __device__ __forceinline__ void bar_lgkm() {
  asm volatile("s_waitcnt lgkmcnt(0)" ::: "memory");
  __builtin_amdgcn_s_barrier();
  __builtin_amdgcn_sched_barrier(0);
}

// ---------------------------------------------------------------------------
// Kernel 1 (r11/r12 best): Cpart[xcd] += x^T x. grid 1280 x 512 thr (8
// waves), wave tile 64x32 (acc 32 VGPR), waves 0-3 stage A, 4-7 stage B,
// CVOFF conflict-free slots, reg-prefetch + LDS dbuf + lgkm-only barrier.
// ---------------------------------------------------------------------------
__global__ __launch_bounds__(512) void covar_k(const float* __restrict__ x,
                                               float* __restrict__ Cpart,
                                               short* __restrict__ xb16) {
  __shared__ short ldsT[2][2][128 * 32];  // [dbuf][A,B][tile] = 32 KB

  // bijective XCD swizzle: 1280 works = 8 XCDs x 160
  const int hw = blockIdx.x;
  const int work = (hw & 7) * 160 + (hw >> 3);
  int t = work % 10, mb = 0, rl = 4;
  while (t >= rl) { t -= rl; ++mb; --rl; }
  const int nb = mb + t;
  const int chunk = work / 10;
  float* C = Cpart + (size_t)(hw & 7) * (D * D);

  const int tid = threadIdx.x;
  const int lane = tid & 63;
  const int wave = tid >> 6;   // 0..7
  const int isB = wave >> 2;   // staging role: 0 = A tile, 1 = B tile
  const int kh = wave & 3;     // staged k-chunk (8 rows)
  const int c2 = lane * 2;     // staged column pair

  const int wr = wave >> 2, wc = wave & 3;  // MFMA wave tile 64(m) x 32(n)
  const int l15 = lane & 15, g = lane >> 4;

  const bool offd = (nb != mb);
  const bool doStage = (!isB) || offd;
  const int tileCol = (isB ? nb : mb) * 128;

  const bool haveDump = (xb16 != nullptr);
  const int rank = isB ? (4 - (nb - mb)) : (nb - mb);
  const bool dump = haveDump && doStage && (kh == rank);
  uint32_t* xw = (uint32_t*)xb16;

  f32x4 acc[4][2];
#pragma unroll
  for (int i = 0; i < 4; ++i)
#pragma unroll
    for (int j = 0; j < 2; ++j) acc[i][j] = f32x4{0.f, 0.f, 0.f, 0.f};

  const size_t kbase0 = (size_t)chunk * CK_ROWS;
  const float* srcBase = x + (kbase0 + kh * 8) * D + tileCol + c2;

  float2 buf[8];
  if (doStage) {
#pragma unroll
    for (int q = 0; q < 8; ++q) buf[q] = *(const float2*)(srcBase + (size_t)q * D);
  }

  for (int st = 0; st < CK_STEPS; ++st) {
    if (doStage) {
      s16x8 p0, p1;
#pragma unroll
      for (int q = 0; q < 8; ++q) {
        p0[q] = (short)f2bf(buf[q].x);
        p1[q] = (short)f2bf(buf[q].y);
      }
      if (st + 1 < CK_STEPS) {
        const float* src = srcBase + (size_t)(st + 1) * BKC * D;
#pragma unroll
        for (int q = 0; q < 8; ++q) buf[q] = *(const float2*)(src + (size_t)q * D);
      }
      short* wp = ldsT[st & 1][isB];
      *(s16x8*)(wp + CVOFF(c2, kh)) = p0;
      *(s16x8*)(wp + CVOFF(c2 + 1, kh)) = p1;
      if (dump) {
        const size_t k0 = kbase0 + (size_t)st * BKC;
#pragma unroll
        for (int q = 0; q < 8; ++q) {
          const uint32_t u = (uint32_t)(uint16_t)p0[q] |
                             ((uint32_t)(uint16_t)p1[q] << 16);
          __builtin_nontemporal_store(
              u, &xw[(k0 + kh * 8 + q) * 256 + (tileCol >> 1) + lane]);
        }
      }
    }

    bar_lgkm();  // publish ds_writes; NO vmcnt drain

    const short* rA = ldsT[st & 1][0];
    const short* rB = ldsT[st & 1][offd ? 1 : 0];
    s16x8 af[4], bfv[2];
#pragma unroll
    for (int mi = 0; mi < 4; ++mi) {
      const int m = 64 * wr + 16 * mi + l15;
      af[mi] = *(const s16x8*)(rA + CVOFF(m, g));
    }
#pragma unroll
    for (int nj = 0; nj < 2; ++nj) {
      const int n = 32 * wc + 16 * nj + l15;
      bfv[nj] = *(const s16x8*)(rB + CVOFF(n, g));
    }
#pragma unroll
    for (int mi = 0; mi < 4; ++mi)
#pragma unroll
      for (int nj = 0; nj < 2; ++nj)
        acc[mi][nj] = mfma16(af[mi], bfv[nj], acc[mi][nj]);
  }

  // epilogue: atomic accumulate into this XCD's partial buffer
#pragma unroll
  for (int mi = 0; mi < 4; ++mi)
#pragma unroll
    for (int nj = 0; nj < 2; ++nj) {
      const int n = nb * 128 + 32 * wc + 16 * nj + l15;
#pragma unroll
      for (int r = 0; r < 4; ++r) {
        const int m = mb * 128 + 64 * wr + 16 * mi + 4 * g + r;
        atomicAdd(&C[(size_t)m * D + n], acc[mi][nj][r]);
      }
    }
}

// ---------------------------------------------------------------------------
// Kernel 2: M = max(0.1*run + (0.9/N)*sum_p Cpart[p], 1e-5); sMax = max rowsum
// ---------------------------------------------------------------------------
__global__ __launch_bounds__(256) void prep_k(const float* __restrict__ Cpart,
                                              const float* __restrict__ run,
                                              float* __restrict__ M,
                                              unsigned* __restrict__ sMax) {
  const int r = blockIdx.x;
  const int t = threadIdx.x;
  const float cs = 0.9f / (float)N_ROWS;
  float sum = 0.f;
  for (int c = t; c < D; c += 256) {
    const int rr = r < c ? r : c;
    const int cc = r < c ? c : r;
    float cv = 0.f;
#pragma unroll
    for (int p = 0; p < 8; ++p)
      cv += Cpart[(size_t)p * D * D + (size_t)rr * D + cc];
    float v = 0.1f * run[(size_t)r * D + c] + cs * cv;
    v = fmaxf(v, 1e-5f);
    M[(size_t)r * D + c] = v;
    sum += v;
  }
  __shared__ float red[256];
  red[t] = sum;
  __syncthreads();
  for (int off = 128; off > 0; off >>= 1) {
    if (t < off) red[t] += red[t + off];
    __syncthreads();
  }
  if (t == 0) atomicMax(sMax, __float_as_uint(red[0]));
}

// ---------------------------------------------------------------------------
// Kernel 3: iter-1 shortcut. Y0 = M/s; T1 = 1.5I - 0.5*Y0; Z1 = T1.
// ---------------------------------------------------------------------------
__global__ __launch_bounds__(256) void init2_k(const float* __restrict__ M,
                                               const unsigned* __restrict__ sMax,
                                               float* __restrict__ Y0,
                                               float* __restrict__ T,
                                               float* __restrict__ Z1) {
  const float inv = 1.0f / __uint_as_float(*sMax);
  const int i0 = (blockIdx.x * 256 + threadIdx.x) * 4;
  const float4 m4 = *(const float4*)&M[i0];
  const int row = i0 >> 9, col0 = i0 & 511;
  float y[4], tv[4];
#pragma unroll
  for (int e = 0; e < 4; ++e) {
    y[e] = (&m4.x)[e] * inv;
    tv[e] = (row == col0 + e ? 1.5f : 0.f) - 0.5f * y[e];
  }
  *(float4*)&Y0[i0] = make_float4(y[0], y[1], y[2], y[3]);
  const float4 t4 = make_float4(tv[0], tv[1], tv[2], tv[3]);
  *(float4*)&T[i0] = t4;
  *(float4*)&Z1[i0] = t4;
}

// ---------------------------------------------------------------------------
// 512x512x512 fp32 matmul body (32x32 tile / block, 2x2 per thread)
// ---------------------------------------------------------------------------
__device__ __forceinline__ void mm512_body(const float* __restrict__ A,
                                           const float* __restrict__ B,
                                           float* a00, float* a01, float* a10,
                                           float* a11, int rbase, int cbase) {
  __shared__ float As[32][36];
  __shared__ float Bs[32][36];
  const int t = threadIdx.x;
  const int tx = t & 15, ty = t >> 4;
  const int sr = t >> 3, sc = (t & 7) * 4;
  float c00 = 0.f, c01 = 0.f, c10 = 0.f, c11 = 0.f;
  for (int k0 = 0; k0 < D; k0 += 32) {
    __syncthreads();
    *(float4*)&As[sr][sc] = *(const float4*)(A + (size_t)(rbase + sr) * D + k0 + sc);
    *(float4*)&Bs[sr][sc] = *(const float4*)(B + (size_t)(k0 + sr) * D + cbase + sc);
    __syncthreads();
#pragma unroll
    for (int kk = 0; kk < 32; ++kk) {
      const float av0 = As[2 * ty][kk], av1 = As[2 * ty + 1][kk];
      const float2 bv = *(const float2*)&Bs[kk][2 * tx];
      c00 = fmaf(av0, bv.x, c00);
      c01 = fmaf(av0, bv.y, c01);
      c10 = fmaf(av1, bv.x, c10);
      c11 = fmaf(av1, bv.y, c11);
    }
  }
  *a00 = c00; *a01 = c01; *a10 = c10; *a11 = c11;
}

// O = A @ B (plain store)
__global__ __launch_bounds__(256) void mmY_k(const float* __restrict__ A,
                                             const float* __restrict__ B,
                                             float* __restrict__ O) {
  const int rbase = blockIdx.y * 32, cbase = blockIdx.x * 32;
  float a00, a01, a10, a11;
  mm512_body(A, B, &a00, &a01, &a10, &a11, rbase, cbase);
  const int tx = threadIdx.x & 15, ty = threadIdx.x >> 4;
  const int r0 = rbase + 2 * ty, c0 = cbase + 2 * tx;
  O[(size_t)r0 * D + c0] = a00;
  O[(size_t)r0 * D + c0 + 1] = a01;
  O[(size_t)(r0 + 1) * D + c0] = a10;
  O[(size_t)(r0 + 1) * D + c0 + 1] = a11;
}

// T = 1.5 I - 0.5 * (Z @ Y)
__global__ __launch_bounds__(256) void mmT_k(const float* __restrict__ Zm,
                                             const float* __restrict__ Ym,
                                             float* __restrict__ T) {
  const int rbase = blockIdx.y * 32, cbase = blockIdx.x * 32;
  float a00, a01, a10, a11;
  mm512_body(Zm, Ym, &a00, &a01, &a10, &a11, rbase, cbase);
  const int tx = threadIdx.x & 15, ty = threadIdx.x >> 4;
  const int r0 = rbase + 2 * ty, c0 = cbase + 2 * tx;
  T[(size_t)r0 * D + c0] = (r0 == c0 ? 1.5f : 0.f) - 0.5f * a00;
  T[(size_t)r0 * D + c0 + 1] = (r0 == c0 + 1 ? 1.5f : 0.f) - 0.5f * a01;
  T[(size_t)(r0 + 1) * D + c0] = (r0 + 1 == c0 ? 1.5f : 0.f) - 0.5f * a10;
  T[(size_t)(r0 + 1) * D + c0 + 1] = (r0 + 1 == c0 + 1 ? 1.5f : 0.f) - 0.5f * a11;
}

// z=0: Ynew = Y @ T ; z=1: Znew = T @ Z
__global__ __launch_bounds__(256) void mmpair_k(const float* __restrict__ Y,
                                                const float* __restrict__ Z,
                                                const float* __restrict__ T,
                                                float* __restrict__ Yn,
                                                float* __restrict__ Zn) {
  const float* A = blockIdx.z ? T : Y;
  const float* B = blockIdx.z ? Z : T;
  float* O = blockIdx.z ? Zn : Yn;
  const int rbase = blockIdx.y * 32, cbase = blockIdx.x * 32;
  float a00, a01, a10, a11;
  mm512_body(A, B, &a00, &a01, &a10, &a11, rbase, cbase);
  const int tx = threadIdx.x & 15, ty = threadIdx.x >> 4;
  const int r0 = rbase + 2 * ty, c0 = cbase + 2 * tx;
  O[(size_t)r0 * D + c0] = a00;
  O[(size_t)r0 * D + c0 + 1] = a01;
  O[(size_t)(r0 + 1) * D + c0] = a10;
  O[(size_t)(r0 + 1) * D + c0 + 1] = a11;
}

// ---------------------------------------------------------------------------
// Kernel 4 (final NS iter, fused): Zfinal = T @ Z, written as pre-swizzled
// bf16 panels (BK=32 layout) scaled by 1/sqrt(s).
// panel layout: [nb(4)][ks(16)][nl(128)][ch'(4)][e(8)] bf16 (512 KB)
// ---------------------------------------------------------------------------
__global__ __launch_bounds__(256) void mmZp_k(const float* __restrict__ T,
                                              const float* __restrict__ Z,
                                              const unsigned* __restrict__ sMax,
                                              short* __restrict__ panels) {
  const int rbase = blockIdx.y * 32, cbase = blockIdx.x * 32;
  float a00, a01, a10, a11;
  mm512_body(T, Z, &a00, &a01, &a10, &a11, rbase, cbase);
  const float rs = rsqrtf(__uint_as_float(*sMax));
  const int tx = threadIdx.x & 15, ty = threadIdx.x >> 4;
  const int r0 = rbase + 2 * ty, c0 = cbase + 2 * tx;
  const float vv[2][2] = {{a00, a01}, {a10, a11}};
#pragma unroll
  for (int dr = 0; dr < 2; ++dr)
#pragma unroll
    for (int dc = 0; dc < 2; ++dc) {
      const int k = r0 + dr, n = c0 + dc;
      const int nb_ = n >> 7, nl = n & 127;
      const int ks = k >> 5, kl = k & 31;
      const int ch = (kl >> 3) ^ ((nl >> 1) & 3), e = kl & 7;
      const size_t pi = (size_t)((nb_ * 16 + ks) * 128 + nl) * 32 + ch * 8 + e;
      panels[pi] = (short)f2bf(vv[dr][dc] * rs);
    }
}

// ---------------------------------------------------------------------------
// Kernel 5 (r12): out = x @ B. grid 8192, 256 thr, BK=32, 32KB LDS,
// 2-deep counted-vmcnt DMA pipeline, GSW both-sides swizzle.
// ---------------------------------------------------------------------------
__global__ __launch_bounds__(256) void gemm_k(const short* __restrict__ xb16,
                                              const short* __restrict__ panels,
                                              float* __restrict__ out) {
  __shared__ short lds[4][128 * 32];  // [0,1]=A dbuf, [2,3]=B dbuf (32 KB)

  const int hw = blockIdx.x;
  const int q = hw & 7, j = hw >> 3;
  const int ct = j & 3;
  const int rp = ((j >> 2) << 3) | q;
  const size_t rbase = (size_t)rp * 128;

  const int tid = threadIdx.x;
  const int lane = tid & 63, wave = tid >> 6;
  const int wr = wave >> 1, wc = wave & 1;
  const int l15 = lane & 15, g = lane >> 4;

  f32x4 acc[4][4];
#pragma unroll
  for (int i = 0; i < 4; ++i)
#pragma unroll
    for (int j2 = 0; j2 < 4; ++j2) acc[i][j2] = f32x4{0.f, 0.f, 0.f, 0.f};

  auto STAGE = [&](int buf, int ksv) {
#pragma unroll
    for (int i = 0; i < 2; ++i) {
      const int rowbase = wave * 32 + i * 16;
      const int m = rowbase + (lane >> 2);
      const short* src =
          xb16 + (rbase + m) * D + ksv * 32 + GSW(m, lane & 3);
      gld_lds16(src, &lds[buf][rowbase * 32]);
    }
    const short* srcB = panels + ((size_t)(ct * 16 + ksv) << 12);
#pragma unroll
    for (int i = 0; i < 2; ++i)
      gld_lds16(srcB + wave * 1024 + i * 512 + lane * 8,
                &lds[2 + buf][wave * 1024 + i * 512]);
  };

  STAGE(0, 0);  // prologue

  for (int ks = 0; ks < 16; ++ks) {
    const int cur = ks & 1;
    if (ks < 15) {
      STAGE(cur ^ 1, ks + 1);
      asm volatile("s_waitcnt vmcnt(4)" ::: "memory");
    } else {
      asm volatile("s_waitcnt vmcnt(0)" ::: "memory");
    }
    __builtin_amdgcn_s_barrier();
    __builtin_amdgcn_sched_barrier(0);

    const short* rA = lds[cur];
    const short* rB = lds[2 + cur];
    s16x8 af[4], bfv[4];
#pragma unroll
    for (int mi = 0; mi < 4; ++mi) {
      const int m = 64 * wr + 16 * mi + l15;
      af[mi] = *(const s16x8*)(rA + m * 32 + GSW(m, g));
    }
#pragma unroll
    for (int nj = 0; nj < 4; ++nj) {
      const int n = 64 * wc + 16 * nj + l15;
      bfv[nj] = *(const s16x8*)(rB + n * 32 + GSW(n, g));
    }
#pragma unroll
    for (int mi = 0; mi < 4; ++mi)
#pragma unroll
      for (int nj = 0; nj < 4; ++nj)
        acc[mi][nj] = mfma16(af[mi], bfv[nj], acc[mi][nj]);

    asm volatile("s_waitcnt lgkmcnt(0)" ::: "memory");
    __builtin_amdgcn_s_barrier();
    __builtin_amdgcn_sched_barrier(0);
  }

  // epilogue: per-wave transpose through LDS, contiguous float4 NT stores
  float* scratch = (float*)&lds[0][0];
  const int wbase = wave * 1088;
#pragma unroll
  for (int mi = 0; mi < 4; ++mi) {
#pragma unroll
    for (int nj = 0; nj < 4; ++nj)
#pragma unroll
      for (int r = 0; r < 4; ++r)
        scratch[wbase + (4 * g + r) * 68 + 16 * nj + l15] = acc[mi][nj][r];
    __syncthreads();
#pragma unroll
    for (int i = 0; i < 4; ++i) {
      const int rl = g + 4 * i;
      const f32x4 v = *(const f32x4*)&scratch[wbase + rl * 68 + l15 * 4];
      const size_t row_g = rbase + 64 * wr + 16 * mi + rl;
      const int col_g = ct * 128 + 64 * wc + l15 * 4;
      __builtin_nontemporal_store(v, (f32x4*)(out + row_g * D + col_g));
    }
    __syncthreads();
  }
}

// ---------------------------------------------------------------------------
// Fallback (ws too small for xb16): A from fp32 x with f2bf, BK=32 layout.
// ---------------------------------------------------------------------------
__global__ __launch_bounds__(256) void gemm_fb_k(const float* __restrict__ x,
                                                 const short* __restrict__ panels,
                                                 float* __restrict__ out) {
  __shared__ short lds[2][128 * 32];

  const int hw = blockIdx.x;
  const int q = hw & 7, j = hw >> 3;
  const int ct = j & 3;
  const int rp = ((j >> 2) << 3) | q;
  const size_t rbase = (size_t)rp * 128;

  const int tid = threadIdx.x;
  const int lane = tid & 63, wave = tid >> 6;
  const int wr = wave >> 1, wc = wave & 1;
  const int l15 = lane & 15, g = lane >> 4;

  const int am = tid >> 1;
  const int ak0 = (tid & 1) * 16;

  f32x4 acc[4][4];
#pragma unroll
  for (int i = 0; i < 4; ++i)
#pragma unroll
    for (int j2 = 0; j2 < 4; ++j2) acc[i][j2] = f32x4{0.f, 0.f, 0.f, 0.f};

  for (int ks = 0; ks < 16; ++ks) {
    __syncthreads();
    {
      s16x8 p;
#pragma unroll
      for (int h = 0; h < 2; ++h) {
        const float4 a =
            *(const float4*)(x + (rbase + am) * D + ks * 32 + ak0 + h * 8);
        const float4 b =
            *(const float4*)(x + (rbase + am) * D + ks * 32 + ak0 + h * 8 + 4);
        p[0] = (short)f2bf(a.x); p[1] = (short)f2bf(a.y);
        p[2] = (short)f2bf(a.z); p[3] = (short)f2bf(a.w);
        p[4] = (short)f2bf(b.x); p[5] = (short)f2bf(b.y);
        p[6] = (short)f2bf(b.z); p[7] = (short)f2bf(b.w);
        const int ch = (ak0 >> 3) + h;
        *(s16x8*)(&lds[0][am * 32] + GSW(am, ch)) = p;
      }
    }
    {
      const short* srcB = panels + ((size_t)(ct * 16 + ks) << 12);
#pragma unroll
      for (int i = 0; i < 2; ++i)
        gld_lds16(srcB + wave * 1024 + i * 512 + lane * 8,
                  &lds[1][wave * 1024 + i * 512]);
    }
    __syncthreads();

    s16x8 af[4], bfv[4];
#pragma unroll
    for (int mi = 0; mi < 4; ++mi) {
      const int m = 64 * wr + 16 * mi + l15;
      af[mi] = *(const s16x8*)(&lds[0][m * 32] + GSW(m, g));
    }
#pragma unroll
    for (int nj = 0; nj < 4; ++nj) {
      const int n = 64 * wc + 16 * nj + l15;
      bfv[nj] = *(const s16x8*)(&lds[1][n * 32] + GSW(n, g));
    }
#pragma unroll
    for (int mi = 0; mi < 4; ++mi)
#pragma unroll
      for (int nj = 0; nj < 4; ++nj)
        acc[mi][nj] = mfma16(af[mi], bfv[nj], acc[mi][nj]);
  }

  __syncthreads();
  float* scratch = (float*)&lds[0][0];
  const int wbase = wave * 1088;
#pragma unroll
  for (int mi = 0; mi < 4; ++mi) {
#pragma unroll
    for (int nj = 0; nj < 4; ++nj)
#pragma unroll
      for (int r = 0; r < 4; ++r)
        scratch[wbase + (4 * g + r) * 68 + 16 * nj + l15] = acc[mi][nj][r];
    __syncthreads();
#pragma unroll
    for (int i = 0; i < 4; ++i) {
      const int rl = g + 4 * i;
      const f32x4 v = *(const f32x4*)&scratch[wbase + rl * 68 + l15 * 4];
      const size_t row_g = rbase + 64 * wr + 16 * mi + rl;
      const int col_g = ct * 128 + 64 * wc + l15 * 4;
      __builtin_nontemporal_store(v, (f32x4*)(out + row_g * D + col_g));
    }
    __syncthreads();
  }
}

// ---------------------------------------------------------------------------
extern "C" void kernel_launch(void* const* d_in, const int* in_sizes, int n_in,
                              void* d_out, int out_size, void* d_ws,
                              size_t ws_size, hipStream_t stream) {
  (void)in_sizes; (void)n_in; (void)out_size;
  const float* x = (const float*)d_in[0];
  const float* run = (const float*)d_in[1];
  float* out = (float*)d_out;
  uint8_t* ws = (uint8_t*)d_ws;

  float* Cpart = (float*)ws;                          // 8 MB (8 x 1MB)
  unsigned* sMax = (unsigned*)(ws + (8u << 20));      // 256 B slot
  float* M = (float*)(ws + (8u << 20) + 256);         // 1 MB
  float* Ya = M + 262144;
  float* Yb = Ya + 262144;
  float* Za = Yb + 262144;
  float* Zb = Za + 262144;
  float* T = Zb + 262144;
  short* panels = (short*)(T + 262144);               // 512 KB
  short* xb16 = panels + 262144;                      // 256 MB (optional)

  const size_t need =
      (size_t)((uint8_t*)xb16 - ws) + (size_t)N_ROWS * D * sizeof(short);
  const bool big = ws_size >= need;

  (void)hipMemsetAsync(Cpart, 0, (8u << 20) + 256, stream);

  covar_k<<<1280, 512, 0, stream>>>(x, Cpart, big ? xb16 : nullptr);
  prep_k<<<512, 256, 0, stream>>>(Cpart, run, M, sMax);

  // NS iter 1 (Z0 = I): T1 elementwise, Z1 = T1, Y1 = Y0 @ T1
  init2_k<<<256, 256, 0, stream>>>(M, sMax, Ya, T, Za);
  mmY_k<<<dim3(16, 16), 256, 0, stream>>>(Ya, T, Yb);

  // NS iters 2..NS_ITERS-1 (full coupled)
  float *Y = Yb, *Z = Za, *Yn = Ya, *Zn = Zb;
  for (int it = 1; it < NS_ITERS - 1; ++it) {
    mmT_k<<<dim3(16, 16), 256, 0, stream>>>(Z, Y, T);
    mmpair_k<<<dim3(16, 16, 2), 256, 0, stream>>>(Y, Z, T, Yn, Zn);
    float* t1 = Y; Y = Yn; Yn = t1;
    t1 = Z; Z = Zn; Zn = t1;
  }

  // final NS iter: only Z needed; fused panel build (BK=32 layout)
  mmT_k<<<dim3(16, 16), 256, 0, stream>>>(Z, Y, T);
  mmZp_k<<<dim3(16, 16), 256, 0, stream>>>(T, Z, sMax, panels);

  if (big)
    gemm_k<<<8192, 256, 0, stream>>>(xb16, panels, out);
  else
    gemm_fb_k<<<8192, 256, 0, stream>>>(x, panels, out);
}